// Round 5
// baseline (467.803 us; speedup 1.0000x reference)
//
#include <hip/hip_runtime.h>

// LocalExpansion: out[b,h,(y,x),c,d] = in[b,h,(y+i-3,x+j-3),d], c = i*7+j,
// zero-filled outside the image.
//
// v12 = LDS row-staging restructure (decisive read-side vs store-side test).
// History: v8 baseline kernel-side ~164-172 us (bench ~460 minus ~292 us
// harness poison fill) vs 73 us write floor. v10 (nt stores) NEUTRAL.
// v11 (+XCD chunked swizzle) NEUTRAL. Both cache-level read-locality fixes
// dead -> stop hoping the cache captures the 49x input reuse; bound it by
// construction. Each block stages its input halo into LDS ONCE: chip-wide
// HBM reads ~22 MB (vs 462 MB logical), kernel becomes write-only at HBM
// level regardless of L2 behavior.
//
// Geometry: block = (bh, y, 16-px strip): 16*48*3 = 2304 blocks, 256 thr.
//   LDS: 7 rows x 22 px (16 + 2*3 halo) x 16 f4 = 2464 float4 = 39,424 B.
//   Output per block: 16 px x 49 c x 16 f4 = 12,544 f4 = 200.7 KB, one
//   contiguous span; 49 store iterations, each 256-lane contiguous.
//   LDS reads: wave reads ~1 KB contiguous (j-consecutive c -> lx
//   consecutive) -> ds_read_b128, 2-way bank aliasing only (free).
//   OOB handling: staging skips invalid cells (LDS garbage is fine -- the
//   consumer select is a bit-select on inb computed from absolute coords,
//   no FP arithmetic touches the garbage).
// Keep: nt stores (write-once output), bijective chunked XCD swizzle
// (2304 % 8 == 0; gives each XCD contiguous (bh,y) range so staging reads
// of adjacent y overlap in its L2).

#define KH 7
#define KW 7
#define HEIGHT 48
#define WIDTH 48
#define DDIM 64
#define D4 (DDIM / 4)            // 16
#define NPIX (HEIGHT * WIDTH)    // 2304
#define KK (KH * KW)             // 49
#define PX 16                    // output pixels per block
#define HALO ((KH - 1) / 2)      // 3
#define LW (PX + 2 * HALO)       // 22 LDS cols
#define NXCD 8

typedef __attribute__((ext_vector_type(4))) float nt_float4;

__global__ __launch_bounds__(256) void local_expansion_kernel(
    const float* __restrict__ in, float* __restrict__ out) {

    __shared__ nt_float4 lds[KH * LW * D4];  // 7*22*16 = 2464 f4 = 39,424 B

    // Bijective chunked XCD swizzle (gridDim.x = 2304, %8 == 0).
    int cpx = gridDim.x >> 3;
    int bid = (blockIdx.x & (NXCD - 1)) * cpx + (blockIdx.x >> 3);

    int t   = threadIdx.x;
    int bh  = bid / (HEIGHT * (WIDTH / PX));              // /144
    int rem = bid - bh * (HEIGHT * (WIDTH / PX));
    int y   = rem / (WIDTH / PX);                         // /3
    int x0  = (rem - y * (WIDTH / PX)) * PX;

    const nt_float4* inp = (const nt_float4*)in + bh * (NPIX * D4);

    // ---- Stage 7-row halo strip into LDS (once per block) ----
    for (int s = t; s < KH * LW * D4; s += 256) {
        int d4 = s & (D4 - 1);
        int p  = s >> 4;          // 0..153 = r*22 + lx
        int r  = p / LW;
        int lx = p - r * LW;
        int ra = y - HALO + r;    // absolute row
        int ca = x0 - HALO + lx;  // absolute col
        if (((unsigned)ra < (unsigned)HEIGHT) & ((unsigned)ca < (unsigned)WIDTH)) {
            lds[s] = inp[(ra * WIDTH + ca) * D4 + d4];
        }
    }
    __syncthreads();

    // ---- Emit: 49 contiguous 1KB-per-wave store rounds ----
    nt_float4* op = (nt_float4*)out +
                    (size_t)(bh * NPIX + y * WIDTH + x0) * (KK * D4);

    int d4 = t & (D4 - 1);
    int th = t >> 4;
    nt_float4 z = (nt_float4)(0.f);

#pragma unroll 7
    for (int k = 0; k < KK; ++k) {
        int o  = k * 256 + t;     // output f4 offset within block span
        int rm = k * 16 + th;     // o >> 4, range 0..783 = xi*49 + c
        int xi = rm / KK;         // 0..15: pixel within strip
        int c  = rm - xi * KK;    // 0..48: filter index
        int i  = c / KW;
        int j  = c - i * KW;
        int sy  = y + i - HALO;            // absolute source row
        int sxa = x0 + xi + j - HALO;      // absolute source col
        bool inb = ((unsigned)sy < (unsigned)HEIGHT) &
                   ((unsigned)sxa < (unsigned)WIDTH);
        // LDS coords are always in-range by construction: row=i, col=xi+j.
        nt_float4 v = lds[(i * LW + xi + j) * D4 + d4];
        __builtin_nontemporal_store(inb ? v : z, op + o);
    }
}

extern "C" void kernel_launch(void* const* d_in, const int* in_sizes, int n_in,
                              void* d_out, int out_size, void* d_ws, size_t ws_size,
                              hipStream_t stream) {
    const float* x = (const float*)d_in[0];
    float* out = (float*)d_out;

    // out_size = 115,605,504 floats = 28,901,376 float4; per block 12,544
    // -> 2304 blocks exact.
    int total4 = out_size / 4;
    int blocks = total4 / (KK * D4 * PX);
    local_expansion_kernel<<<dim3(blocks), 256, 0, stream>>>(x, out);
}